// Round 4
// baseline (974.524 us; speedup 1.0000x reference)
//
#include <hip/hip_runtime.h>
#include <cstdint>

#define NN 20000     // nodes
#define NE 640000    // edges
#define NB 128       // basis
#define NG 64        // gaussians
#define NH 256       // hidden

typedef __attribute__((ext_vector_type(8))) _Float16 h16x8;
typedef __attribute__((ext_vector_type(4))) float f32x4;
typedef __attribute__((ext_vector_type(4))) float fvec4;
typedef __attribute__((ext_vector_type(4))) unsigned uvec4;

__device__ __forceinline__ unsigned fbits(float f){ union{float f; unsigned u;} v; v.f=f; return v.u; }

// pack two f32 -> packed fp16 dword, round-toward-zero (1 instr): low half = a
__device__ __forceinline__ unsigned pkh(float a, float b){
  auto t = __builtin_amdgcn_cvt_pkrtz(a, b);
  return __builtin_bit_cast(unsigned, t);
}
// pack two f32 -> packed fp16 dword, RNE (for weights; one-time cost)
__device__ __forceinline__ unsigned pkh_rne(float a, float b){
  union{ _Float16 h[2]; unsigned u; } v;
  v.h[0] = (_Float16)a; v.h[1] = (_Float16)b; return v.u;
}
// packed fp16 pair * packed fp16 pair -> packed fp16 products (1 instr)
__device__ __forceinline__ unsigned pkmul(unsigned a, unsigned b){
  unsigned r; asm("v_pk_mul_f16 %0, %1, %2" : "=v"(r) : "v"(a), "v"(b)); return r;
}
__device__ __forceinline__ short f2h(float f){
  union{ _Float16 h[2]; short s[2]; } v; v.h[0] = (_Float16)f; return v.s[0];
}

__device__ __forceinline__ float tanh_fast(float x){
  float t = __builtin_amdgcn_exp2f(x * 2.8853900817779268f);
  return __builtin_fmaf(-2.f, __builtin_amdgcn_rcpf(t + 1.f), 1.f);
}

// Stage W[N=NT*16][K=KT*32] (f32) as fp16 MFMA B-fragments into LDS.
template<int NT, int KT>
__device__ __forceinline__ void stage_w(const float* __restrict__ W, short* lds){
  const int total = NT*KT*64;
  for(int c = (int)threadIdx.x; c < total; c += 256){
    int lane = c & 63;
    int kt = (c >> 6) % KT;
    int n  = c / (64*KT);
    int row = n*16 + (lane & 15);
    int col = kt*32 + (lane >> 4)*8;
    const float* p = W + (size_t)row*(KT*32) + col;
    unsigned* d = (unsigned*)(lds + (size_t)c*8);
#pragma unroll
    for(int j=0;j<4;j++) d[j] = pkh_rne(p[2*j], p[2*j+1]);
  }
}

// ---------------- fused embed + dst histogram ----------------
__global__ void k_prep0(const int* __restrict__ Z, const float* __restrict__ E,
                        float* __restrict__ C, const int* __restrict__ dst, int* __restrict__ cnt){
  int i = blockIdx.x*256 + threadIdx.x;    // exactly NN*32 == NE == 640000
  int node = i >> 5, k4 = i & 31;
  ((float4*)C)[i] = ((const float4*)(E + (size_t)Z[node]*NB))[k4];
  atomicAdd(&cnt[dst[i]], 1);
}

__global__ __launch_bounds__(1024) void k_scan(const int* __restrict__ cnt, int* __restrict__ cur){
  __shared__ int lds[1024];
  const int t = threadIdx.x;
  const int base = t*20;
  int4 v[5];
#pragma unroll
  for(int j=0;j<5;j++) v[j] = ((const int4*)(cnt + base))[j];
  const int* ve = (const int*)v;
  int loc[20]; int s = 0;
#pragma unroll
  for(int j=0;j<20;j++){ int c = (base+j < NN) ? ve[j] : 0; loc[j] = s; s += c; }
  lds[t] = s;
  __syncthreads();
  for(int off=1; off<1024; off<<=1){
    int x = (t >= off) ? lds[t-off] : 0;
    __syncthreads();
    lds[t] += x;
    __syncthreads();
  }
  int prefix = (t > 0) ? lds[t-1] : 0;
#pragma unroll
  for(int j=0;j<20;j++){ int i = base+j; if(i<NN) cur[i] = prefix + loc[j]; }
}

__global__ void k_fill(const int* __restrict__ src, const int* __restrict__ dst,
                       int* __restrict__ cur, int* __restrict__ perm,
                       int2* __restrict__ sd){
  int e = blockIdx.x*256 + threadIdx.x;
  if(e < NE){
    int v = dst[e];
    int p = atomicAdd(&cur[v], 1);
    perm[p] = e;
    sd[p] = make_int2(src[e], v);
  }
}

// ---------------- d_feat = edge_attr[perm] @ dfW.T + dfb  (fp16, perm order, LDS-transposed stores) ----------------
// 2500 blocks x 4 waves x 2 tiles, software-pipelined.
#define TPAD 136
__global__ __launch_bounds__(256,3) void k_dprep(
  const float* __restrict__ ea, const int* __restrict__ perm,
  const float* __restrict__ dfW, const float* __restrict__ dfb, short* __restrict__ dft)
{
  __shared__ short ldsW[8*2*64*8];     // 16 KB
  __shared__ short ldsT[4*32*TPAD];    // 34816 B
  stage_w<8,2>(dfW, ldsW);
  __syncthreads();
  const int lane = threadIdx.x & 63, wave = threadIdx.x >> 6;
  const int quad = lane>>4, lc = lane&15;
  short* myT = ldsT + wave*32*TPAD;
  const int tile0 = (blockIdx.x*4 + wave)*2;   // 2500*4*2 = 20000 tiles exactly

  float bias[8];
#pragma unroll
  for(int n2=0;n2<8;n2++) bias[n2] = dfb[n2*16 + lc];

  // perm indices for both tiles (independent loads, issued together)
  int eA[2], eB[2];
#pragma unroll
  for(int mt=0;mt<2;mt++){
    eA[mt] = perm[ tile0   *32 + mt*16 + lc];
    eB[mt] = perm[(tile0+1)*32 + mt*16 + lc];
  }

  // raw ea gathers, tile A
  fvec4 rA[2][2][2];
#pragma unroll
  for(int mt=0;mt<2;mt++){
    const float* p = ea + (size_t)eA[mt]*NG;
#pragma unroll
    for(int kt=0;kt<2;kt++){
      const float* q = p + kt*32 + quad*8;
      rA[mt][kt][0] = __builtin_nontemporal_load((const fvec4*)q);
      rA[mt][kt][1] = __builtin_nontemporal_load((const fvec4*)(q+4));
    }
  }

  f32x4 z = {0.f,0.f,0.f,0.f};

  auto convert_mfma = [&](fvec4 (&raw)[2][2][2], f32x4 (&acc)[2][8]){
#pragma unroll
    for(int mt=0;mt<2;mt++)
#pragma unroll
      for(int n2=0;n2<8;n2++) acc[mt][n2] = z;
#pragma unroll
    for(int kt=0;kt<2;kt++){
      h16x8 a0, a1;
      {
        union{ h16x8 v; unsigned u[4]; } t0, t1;
        fvec4 c0 = raw[0][kt][0], c1 = raw[0][kt][1];
        fvec4 d0 = raw[1][kt][0], d1 = raw[1][kt][1];
        t0.u[0]=pkh(c0.x,c0.y); t0.u[1]=pkh(c0.z,c0.w); t0.u[2]=pkh(c1.x,c1.y); t0.u[3]=pkh(c1.z,c1.w);
        t1.u[0]=pkh(d0.x,d0.y); t1.u[1]=pkh(d0.z,d0.w); t1.u[2]=pkh(d1.x,d1.y); t1.u[3]=pkh(d1.z,d1.w);
        a0 = t0.v; a1 = t1.v;
      }
#pragma unroll
      for(int n2=0;n2<8;n2++){
        h16x8 b = *(const h16x8*)(ldsW + ((size_t)(n2*2+kt)*64 + lane)*8);
        acc[0][n2] = __builtin_amdgcn_mfma_f32_16x16x32_f16(a0, b, acc[0][n2], 0, 0, 0);
        acc[1][n2] = __builtin_amdgcn_mfma_f32_16x16x32_f16(a1, b, acc[1][n2], 0, 0, 0);
      }
    }
  };

  auto store_tile = [&](f32x4 (&acc)[2][8], int tile){
#pragma unroll
    for(int n2=0;n2<8;n2++)
#pragma unroll
      for(int mt=0;mt<2;mt++)
#pragma unroll
        for(int r=0;r<4;r++)
          myT[(mt*16 + quad*4 + r)*TPAD + n2*16 + lc] = f2h(acc[mt][n2][r] + bias[n2]);
    short* gout = dft + (size_t)tile*32*NB;
#pragma unroll
    for(int i=0;i<8;i++){
      int s_ = i*512 + lane*8;
      int row = s_ >> 7, col = s_ & 127;
      uvec4 vv = *(const uvec4*)(myT + row*TPAD + col);
      __builtin_nontemporal_store(vv, (uvec4*)(gout + s_));
    }
  };

  // tile A: convert + MFMA
  f32x4 accA[2][8];
  convert_mfma(rA, accA);

  // issue tile B's ea gathers now — latency hides under tile A's store phase
  fvec4 rB[2][2][2];
#pragma unroll
  for(int mt=0;mt<2;mt++){
    const float* p = ea + (size_t)eB[mt]*NG;
#pragma unroll
    for(int kt=0;kt<2;kt++){
      const float* q = p + kt*32 + quad*8;
      rB[mt][kt][0] = __builtin_nontemporal_load((const fvec4*)q);
      rB[mt][kt][1] = __builtin_nontemporal_load((const fvec4*)(q+4));
    }
  }

  store_tile(accA, tile0);

  f32x4 accB[2][8];
  convert_mfma(rB, accB);
  store_tile(accB, tile0+1);
}

// ---------------- cfC = fp16(C @ cfW.T + cfb) on nodes, LDS-transposed stores ----------------
__global__ __launch_bounds__(256,3) void k_cf(
  const float* __restrict__ C, const float* __restrict__ cfW,
  const float* __restrict__ cfb, short* __restrict__ cfC)
{
  __shared__ short ldsW[8*4*64*8];     // 32 KB
  __shared__ short ldsT[4*16*TPAD];    // 17408 B
  stage_w<8,4>(cfW, ldsW);
  __syncthreads();
  const int lane = threadIdx.x & 63, wave = threadIdx.x >> 6;
  const int quad = lane>>4, lc = lane&15;
  short* myT = ldsT + wave*16*TPAD;
  const int tile = blockIdx.x*4 + wave;       // 313*4 = 1252 >= 1250 tiles
  if(tile >= NN/16) return;
  const int base = tile*16;
  h16x8 a[4];
  const float* p = C + (size_t)(base + lc)*NB;
#pragma unroll
  for(int kt=0;kt<4;kt++){
    const float* q = p + kt*32 + quad*8;
    float4 c0 = *(const float4*)q, c1 = *(const float4*)(q+4);
    union{ h16x8 v; unsigned u[4]; } t;
    t.u[0]=pkh(c0.x,c0.y); t.u[1]=pkh(c0.z,c0.w); t.u[2]=pkh(c1.x,c1.y); t.u[3]=pkh(c1.z,c1.w);
    a[kt] = t.v;
  }
  f32x4 acc[8];
  f32x4 z = {0.f,0.f,0.f,0.f};
#pragma unroll
  for(int n2=0;n2<8;n2++) acc[n2] = z;
#pragma unroll
  for(int kt=0;kt<4;kt++)
#pragma unroll
    for(int n2=0;n2<8;n2++){
      h16x8 b = *(const h16x8*)(ldsW + ((size_t)(n2*4+kt)*64 + lane)*8);
      acc[n2] = __builtin_amdgcn_mfma_f32_16x16x32_f16(a[kt], b, acc[n2], 0, 0, 0);
    }
#pragma unroll
  for(int n2=0;n2<8;n2++){
    float bias = cfb[n2*16 + lc];
#pragma unroll
    for(int r=0;r<4;r++)
      myT[(quad*4 + r)*TPAD + n2*16 + lc] = f2h(acc[n2][r] + bias);
  }
  short* gout = cfC + (size_t)base*NB;
#pragma unroll
  for(int i=0;i<4;i++){
    int s_ = i*512 + lane*8;
    int row = s_ >> 7, col = s_ & 127;
    uint4 vv = *(const uint4*)(myT + row*TPAD + col);
    *(uint4*)(gout + s_) = vv;
  }
}

// ---------------- edge kernel: software-pipelined tiles, fp16 ----------------
// C += scatter(tanh((cfC[src] * dft) @ fcW.T)), edges dst-sorted, atomics per segment.
// launch_bounds history: (256,2) -> VGPR 112 used under cap 256, occupancy pinned
// at 8 waves/CU (18.5% measured), all pipes idle (MFMA 8.7 / VALU 27 / HBM 21%).
// (256,3) with cap 84 spilled (round-2: WRITE 19.7->71.8 MB). (256,4) caps at 128
// >= 112 need: 16 waves/CU, no spill expected. Watch WRITE_SIZE as spill canary.
#define ETPW 4
__global__ __launch_bounds__(256,4) void k_edge(
    const short* __restrict__ cfC, const short* __restrict__ dft,
    const int2* __restrict__ sd,
    const float* __restrict__ fcW, float* __restrict__ C)
{
  __shared__ short ldsW[8*4*64*8];   // 32 KB
  stage_w<8,4>(fcW, ldsW);
  __syncthreads();
  const int lane = threadIdx.x & 63, wave = threadIdx.x >> 6;
  const int quad = lane>>4, lc = lane&15;
  const int tile0 = (blockIdx.x*4 + wave)*ETPW;  // 1250*4*4 = 20000 tiles exactly

  int   sv[2][2];         // [stage][mt] src node ids
  int   dv[2];            // [stage] dst node id for lane&31
  uint4 cc[2][2][4];      // [stage][mt][kt] raw cfC
  uint4 dd[2][2][4];      // [stage][mt][kt] raw dft

  // ---- prologue: stage 0 = tile0 ----
  {
    const int base = tile0*32;
    int2 s0 = sd[base + (lane&31)];
    dv[0] = s0.y;
    sv[0][0] = __shfl(s0.x, lc);
    sv[0][1] = __shfl(s0.x, 16 + lc);
#pragma unroll
    for(int mt=0;mt<2;mt++){
      const short* dp = dft + (size_t)(base + mt*16 + lc)*NB;
#pragma unroll
      for(int kt=0;kt<4;kt++) dd[0][mt][kt] = *(const uint4*)(dp + kt*32 + quad*8);
    }
#pragma unroll
    for(int mt=0;mt<2;mt++){
      const short* cp = cfC + (size_t)sv[0][mt]*NB;
#pragma unroll
      for(int kt=0;kt<4;kt++) cc[0][mt][kt] = *(const uint4*)(cp + kt*32 + quad*8);
    }
  }

#pragma unroll
  for(int t=0; t<ETPW; t++){
    const int cur = t & 1, nxt = cur ^ 1;

    // ---- issue next tile's index load + dft stream (no srcv dependence) ----
    if(t+1 < ETPW){
      const int nbase = (tile0 + t + 1)*32;
      int2 s0 = sd[nbase + (lane&31)];
      dv[nxt] = s0.y;
      sv[nxt][0] = __shfl(s0.x, lc);
      sv[nxt][1] = __shfl(s0.x, 16 + lc);
#pragma unroll
      for(int mt=0;mt<2;mt++){
        const short* dp = dft + (size_t)(nbase + mt*16 + lc)*NB;
#pragma unroll
        for(int kt=0;kt<4;kt++) dd[nxt][mt][kt] = *(const uint4*)(dp + kt*32 + quad*8);
      }
    }

    // ---- convert (packed fp16 mul) + MFMA current tile ----
    f32x4 acc[2][8];
    f32x4 z = {0.f,0.f,0.f,0.f};
#pragma unroll
    for(int mt=0;mt<2;mt++)
#pragma unroll
      for(int n2=0;n2<8;n2++) acc[mt][n2] = z;
#pragma unroll
    for(int kt=0;kt<4;kt++){
      h16x8 a0, a1;
      {
        union{ h16x8 v; unsigned u[4]; } t0, t1;
        uint4 c0 = cc[cur][0][kt], d0 = dd[cur][0][kt];
        uint4 c1 = cc[cur][1][kt], d1 = dd[cur][1][kt];
        t0.u[0] = pkmul(c0.x, d0.x); t0.u[1] = pkmul(c0.y, d0.y);
        t0.u[2] = pkmul(c0.z, d0.z); t0.u[3] = pkmul(c0.w, d0.w);
        t1.u[0] = pkmul(c1.x, d1.x); t1.u[1] = pkmul(c1.y, d1.y);
        t1.u[2] = pkmul(c1.z, d1.z); t1.u[3] = pkmul(c1.w, d1.w);
        a0 = t0.v; a1 = t1.v;
      }
#pragma unroll
      for(int n2=0;n2<8;n2++){
        h16x8 b = *(const h16x8*)(ldsW + ((size_t)(n2*4 + kt)*64 + lane)*8);
        acc[0][n2] = __builtin_amdgcn_mfma_f32_16x16x32_f16(a0, b, acc[0][n2], 0, 0, 0);
        acc[1][n2] = __builtin_amdgcn_mfma_f32_16x16x32_f16(a1, b, acc[1][n2], 0, 0, 0);
      }
    }

    // ---- issue next tile's cfC gather (srcv arrived while MFMAs ran) ----
    if(t+1 < ETPW){
#pragma unroll
      for(int mt=0;mt<2;mt++){
        const short* cp = cfC + (size_t)sv[nxt][mt]*NB;
#pragma unroll
        for(int kt=0;kt<4;kt++) cc[nxt][mt][kt] = *(const uint4*)(cp + kt*32 + quad*8);
      }
    }

    // ---- tanh ----
#pragma unroll
    for(int mt=0;mt<2;mt++)
#pragma unroll
      for(int n2=0;n2<8;n2++)
#pragma unroll
        for(int r=0;r<4;r++) acc[mt][n2][r] = tanh_fast(acc[mt][n2][r]);

    // ---- segmented reduction over dst (perm-sorted) + quad-distributed atomics ----
    const int i = lane & 31;
    const int di = dv[cur];
    const int dshift = __shfl_up(di, 1);
    const int dprev = (i > 0) ? dshift : -1;
    unsigned long long mm = __ballot(di != dprev) & 0xFFFFFFFFull;
    while(mm){
      int lo = __ffsll(mm) - 1;
      mm &= mm - 1;
      int hi = mm ? (__ffsll(mm) - 1) : 32;
      int v = __shfl(di, lo);
      float sums[8];
#pragma unroll
      for(int n2=0;n2<8;n2++) sums[n2] = 0.f;
#pragma unroll
      for(int mt=0; mt<2; mt++)
#pragma unroll
        for(int r=0; r<4; r++){
          int e2 = mt*16 + quad*4 + r;
          float sel = (e2 >= lo && e2 < hi) ? 1.f : 0.f;
#pragma unroll
          for(int n2=0;n2<8;n2++) sums[n2] = __builtin_fmaf(acc[mt][n2][r], sel, sums[n2]);
        }
#pragma unroll
      for(int n2=0;n2<8;n2++){
        sums[n2] += __shfl_xor(sums[n2], 16);
        sums[n2] += __shfl_xor(sums[n2], 32);
      }
      const int n2w = quad*2;
      atomicAdd(&C[(size_t)v*NB + n2w*16 + lc],     sums[n2w]);
      atomicAdd(&C[(size_t)v*NB + (n2w+1)*16 + lc], sums[n2w+1]);
    }
  }
}

// ---------------- readout: out += pool(tanh(C@r1W.T + r1b)@r2W.T + r2b) ----------------
__global__ __launch_bounds__(256,2) void k_readout(
  const float* __restrict__ C, const float* __restrict__ r1W, const float* __restrict__ r1b,
  const float* __restrict__ r2W, const float* __restrict__ r2b,
  const int* __restrict__ batch, float* __restrict__ out)
{
  __shared__ short ldsW[16*4*64*8];  // 64 KB
  stage_w<16,4>(r1W, ldsW);
  __syncthreads();
  const int lane = threadIdx.x & 63, wave = threadIdx.x >> 6;
  const int quad = lane>>4, lc = lane&15;
  const int base = (blockIdx.x*4 + wave)*16;
  if(base >= NN) return;
  int node = base + lc; if(node > NN-1) node = NN-1;
  h16x8 a[4];
  const float* p = C + (size_t)node*NB;
#pragma unroll
  for(int kt=0;kt<4;kt++){
    const float* q = p + kt*32 + quad*8;
    float4 c0 = *(const float4*)q, c1 = *(const float4*)(q+4);
    union{ h16x8 v; unsigned u[4]; } t;
    t.u[0]=pkh(c0.x,c0.y); t.u[1]=pkh(c0.z,c0.w); t.u[2]=pkh(c1.x,c1.y); t.u[3]=pkh(c1.z,c1.w);
    a[kt] = t.v;
  }
  f32x4 acc[16];
  f32x4 z = {0.f,0.f,0.f,0.f};
#pragma unroll
  for(int nt=0;nt<16;nt++) acc[nt] = z;
#pragma unroll
  for(int kt=0;kt<4;kt++)
#pragma unroll
    for(int nt=0;nt<16;nt++){
      h16x8 b = *(const h16x8*)(ldsW + ((size_t)(nt*4+kt)*64 + lane)*8);
      acc[nt] = __builtin_amdgcn_mfma_f32_16x16x32_f16(a[kt], b, acc[nt], 0, 0, 0);
    }
#pragma unroll
  for(int nt=0;nt<16;nt++){
    float bias = r1b[nt*16 + lc];
#pragma unroll
    for(int r=0;r<4;r++) acc[nt][r] = tanh_fast(acc[nt][r] + bias);
  }
#pragma unroll
  for(int r=0;r<4;r++){
    int nd = base + quad*4 + r;
#pragma unroll
    for(int o=0;o<4;o++){
      float ps = 0.f;
#pragma unroll
      for(int nt=0;nt<16;nt++) ps = __builtin_fmaf(acc[nt][r], r2W[(size_t)o*NH + nt*16 + lc], ps);
      ps += __shfl_xor(ps, 1);
      ps += __shfl_xor(ps, 2);
      ps += __shfl_xor(ps, 4);
      ps += __shfl_xor(ps, 8);
      if(lc == 0 && nd < NN) atomicAdd(&out[batch[nd]*4 + o], ps + r2b[o]);
    }
  }
}

extern "C" void kernel_launch(void* const* d_in, const int* in_sizes, int n_in,
                              void* d_out, int out_size, void* d_ws, size_t ws_size,
                              hipStream_t stream) {
  const int*   Z      = (const int*)d_in[0];
  const int*   ei     = (const int*)d_in[1];
  const float* ea     = (const float*)d_in[2];
  const int*   batch  = (const int*)d_in[3];
  const float* embedW = (const float*)d_in[4];
  const float* cfW    = (const float*)d_in[5];
  const float* cfb    = (const float*)d_in[6];
  const float* dfW    = (const float*)d_in[7];
  const float* dfb    = (const float*)d_in[8];
  const float* fcW    = (const float*)d_in[9];
  const float* r1W    = (const float*)d_in[10];
  const float* r1b    = (const float*)d_in[11];
  const float* r2W    = (const float*)d_in[12];
  const float* r2b    = (const float*)d_in[13];
  const int* src = ei;
  const int* dst = ei + NE;

  char* p = (char*)d_ws;
  auto alloc = [&](size_t b){ char* r = p; p += (b + 255) & ~(size_t)255; return r; };
  float* CA    = (float*)alloc((size_t)NN*NB*4);
  short* cfC   = (short*)alloc((size_t)NN*NB*2);
  short* dft   = (short*)alloc((size_t)NE*NB*2);
  int*   cnt   = (int*)alloc((size_t)NN*4);
  int*   cursor= (int*)alloc((size_t)NN*4);
  int*   perm  = (int*)alloc((size_t)NE*4);
  int2*  sd    = (int2*)alloc((size_t)NE*8);
  size_t needed = (size_t)(p - (char*)d_ws);

  (void)hipMemsetAsync(d_out, 0, (size_t)out_size*sizeof(float), stream);
  if(needed > ws_size) return;   // all-zero output = ws-too-small diagnostic

  (void)hipMemsetAsync(cnt, 0, (size_t)NN*4, stream);
  k_prep0<<<2500, 256, 0, stream>>>(Z, embedW, CA, dst, cnt);
  k_scan <<<1,   1024, 0, stream>>>(cnt, cursor);
  k_fill <<<2500, 256, 0, stream>>>(src, dst, cursor, perm, sd);
  k_dprep<<<2500, 256, 0, stream>>>(ea, perm, dfW, dfb, dft);

  for(int it = 0; it < 3; it++){
    k_cf  <<<313,  256, 0, stream>>>(CA, cfW, cfb, cfC);
    k_edge<<<1250, 256, 0, stream>>>(cfC, dft, sd, fcW, CA);
  }
  k_readout<<<313, 256, 0, stream>>>(CA, r1W, r1b, r2W, r2b, batch, (float*)d_out);
}

// Round 5
// 656.303 us; speedup vs baseline: 1.4849x; 1.4849x over previous
//
#include <hip/hip_runtime.h>
#include <cstdint>

#define NN 20000     // nodes
#define NE 640000    // edges
#define NB 128       // basis
#define NG 64        // gaussians
#define NH 256       // hidden

typedef __attribute__((ext_vector_type(8))) _Float16 h16x8;
typedef __attribute__((ext_vector_type(4))) float f32x4;
typedef __attribute__((ext_vector_type(4))) float fvec4;
typedef __attribute__((ext_vector_type(4))) unsigned uvec4;

__device__ __forceinline__ unsigned fbits(float f){ union{float f; unsigned u;} v; v.f=f; return v.u; }

// pack two f32 -> packed fp16 dword, round-toward-zero (1 instr): low half = a
__device__ __forceinline__ unsigned pkh(float a, float b){
  auto t = __builtin_amdgcn_cvt_pkrtz(a, b);
  return __builtin_bit_cast(unsigned, t);
}
// pack two f32 -> packed fp16 dword, RNE (for weights; one-time cost)
__device__ __forceinline__ unsigned pkh_rne(float a, float b){
  union{ _Float16 h[2]; unsigned u; } v;
  v.h[0] = (_Float16)a; v.h[1] = (_Float16)b; return v.u;
}
// packed fp16 pair * packed fp16 pair -> packed fp16 products (1 instr)
__device__ __forceinline__ unsigned pkmul(unsigned a, unsigned b){
  unsigned r; asm("v_pk_mul_f16 %0, %1, %2" : "=v"(r) : "v"(a), "v"(b)); return r;
}
__device__ __forceinline__ short f2h(float f){
  union{ _Float16 h[2]; short s[2]; } v; v.h[0] = (_Float16)f; return v.s[0];
}

__device__ __forceinline__ float tanh_fast(float x){
  float t = __builtin_amdgcn_exp2f(x * 2.8853900817779268f);
  return __builtin_fmaf(-2.f, __builtin_amdgcn_rcpf(t + 1.f), 1.f);
}

// Stage W[N=NT*16][K=KT*32] (f32) as fp16 MFMA B-fragments into LDS.
template<int NT, int KT>
__device__ __forceinline__ void stage_w(const float* __restrict__ W, short* lds){
  const int total = NT*KT*64;
  for(int c = (int)threadIdx.x; c < total; c += 256){
    int lane = c & 63;
    int kt = (c >> 6) % KT;
    int n  = c / (64*KT);
    int row = n*16 + (lane & 15);
    int col = kt*32 + (lane >> 4)*8;
    const float* p = W + (size_t)row*(KT*32) + col;
    unsigned* d = (unsigned*)(lds + (size_t)c*8);
#pragma unroll
    for(int j=0;j<4;j++) d[j] = pkh_rne(p[2*j], p[2*j+1]);
  }
}

// ---------------- fused embed + dst histogram ----------------
__global__ void k_prep0(const int* __restrict__ Z, const float* __restrict__ E,
                        float* __restrict__ C, const int* __restrict__ dst, int* __restrict__ cnt){
  int i = blockIdx.x*256 + threadIdx.x;    // exactly NN*32 == NE == 640000
  int node = i >> 5, k4 = i & 31;
  ((float4*)C)[i] = ((const float4*)(E + (size_t)Z[node]*NB))[k4];
  atomicAdd(&cnt[dst[i]], 1);
}

__global__ __launch_bounds__(1024) void k_scan(const int* __restrict__ cnt, int* __restrict__ cur){
  __shared__ int lds[1024];
  const int t = threadIdx.x;
  const int base = t*20;
  int4 v[5];
#pragma unroll
  for(int j=0;j<5;j++) v[j] = ((const int4*)(cnt + base))[j];
  const int* ve = (const int*)v;
  int loc[20]; int s = 0;
#pragma unroll
  for(int j=0;j<20;j++){ int c = (base+j < NN) ? ve[j] : 0; loc[j] = s; s += c; }
  lds[t] = s;
  __syncthreads();
  for(int off=1; off<1024; off<<=1){
    int x = (t >= off) ? lds[t-off] : 0;
    __syncthreads();
    lds[t] += x;
    __syncthreads();
  }
  int prefix = (t > 0) ? lds[t-1] : 0;
#pragma unroll
  for(int j=0;j<20;j++){ int i = base+j; if(i<NN) cur[i] = prefix + loc[j]; }
}

__global__ void k_fill(const int* __restrict__ src, const int* __restrict__ dst,
                       int* __restrict__ cur, int* __restrict__ perm,
                       int2* __restrict__ sd){
  int e = blockIdx.x*256 + threadIdx.x;
  if(e < NE){
    int v = dst[e];
    int p = atomicAdd(&cur[v], 1);
    perm[p] = e;
    sd[p] = make_int2(src[e], v);
  }
}

// ---------------- d_feat = edge_attr[perm] @ dfW.T + dfb  (fp16, perm order, LDS-transposed stores) ----------------
// 2500 blocks x 4 waves x 2 tiles, software-pipelined.
#define TPAD 136
__global__ __launch_bounds__(256,3) void k_dprep(
  const float* __restrict__ ea, const int* __restrict__ perm,
  const float* __restrict__ dfW, const float* __restrict__ dfb, short* __restrict__ dft)
{
  __shared__ short ldsW[8*2*64*8];     // 16 KB
  __shared__ short ldsT[4*32*TPAD];    // 34816 B
  stage_w<8,2>(dfW, ldsW);
  __syncthreads();
  const int lane = threadIdx.x & 63, wave = threadIdx.x >> 6;
  const int quad = lane>>4, lc = lane&15;
  short* myT = ldsT + wave*32*TPAD;
  const int tile0 = (blockIdx.x*4 + wave)*2;   // 2500*4*2 = 20000 tiles exactly

  float bias[8];
#pragma unroll
  for(int n2=0;n2<8;n2++) bias[n2] = dfb[n2*16 + lc];

  // perm indices for both tiles (independent loads, issued together)
  int eA[2], eB[2];
#pragma unroll
  for(int mt=0;mt<2;mt++){
    eA[mt] = perm[ tile0   *32 + mt*16 + lc];
    eB[mt] = perm[(tile0+1)*32 + mt*16 + lc];
  }

  // raw ea gathers, tile A
  fvec4 rA[2][2][2];
#pragma unroll
  for(int mt=0;mt<2;mt++){
    const float* p = ea + (size_t)eA[mt]*NG;
#pragma unroll
    for(int kt=0;kt<2;kt++){
      const float* q = p + kt*32 + quad*8;
      rA[mt][kt][0] = __builtin_nontemporal_load((const fvec4*)q);
      rA[mt][kt][1] = __builtin_nontemporal_load((const fvec4*)(q+4));
    }
  }

  f32x4 z = {0.f,0.f,0.f,0.f};

  auto convert_mfma = [&](fvec4 (&raw)[2][2][2], f32x4 (&acc)[2][8]){
#pragma unroll
    for(int mt=0;mt<2;mt++)
#pragma unroll
      for(int n2=0;n2<8;n2++) acc[mt][n2] = z;
#pragma unroll
    for(int kt=0;kt<2;kt++){
      h16x8 a0, a1;
      {
        union{ h16x8 v; unsigned u[4]; } t0, t1;
        fvec4 c0 = raw[0][kt][0], c1 = raw[0][kt][1];
        fvec4 d0 = raw[1][kt][0], d1 = raw[1][kt][1];
        t0.u[0]=pkh(c0.x,c0.y); t0.u[1]=pkh(c0.z,c0.w); t0.u[2]=pkh(c1.x,c1.y); t0.u[3]=pkh(c1.z,c1.w);
        t1.u[0]=pkh(d0.x,d0.y); t1.u[1]=pkh(d0.z,d0.w); t1.u[2]=pkh(d1.x,d1.y); t1.u[3]=pkh(d1.z,d1.w);
        a0 = t0.v; a1 = t1.v;
      }
#pragma unroll
      for(int n2=0;n2<8;n2++){
        h16x8 b = *(const h16x8*)(ldsW + ((size_t)(n2*2+kt)*64 + lane)*8);
        acc[0][n2] = __builtin_amdgcn_mfma_f32_16x16x32_f16(a0, b, acc[0][n2], 0, 0, 0);
        acc[1][n2] = __builtin_amdgcn_mfma_f32_16x16x32_f16(a1, b, acc[1][n2], 0, 0, 0);
      }
    }
  };

  auto store_tile = [&](f32x4 (&acc)[2][8], int tile){
#pragma unroll
    for(int n2=0;n2<8;n2++)
#pragma unroll
      for(int mt=0;mt<2;mt++)
#pragma unroll
        for(int r=0;r<4;r++)
          myT[(mt*16 + quad*4 + r)*TPAD + n2*16 + lc] = f2h(acc[mt][n2][r] + bias[n2]);
    short* gout = dft + (size_t)tile*32*NB;
#pragma unroll
    for(int i=0;i<8;i++){
      int s_ = i*512 + lane*8;
      int row = s_ >> 7, col = s_ & 127;
      uvec4 vv = *(const uvec4*)(myT + row*TPAD + col);
      __builtin_nontemporal_store(vv, (uvec4*)(gout + s_));
    }
  };

  // tile A: convert + MFMA
  f32x4 accA[2][8];
  convert_mfma(rA, accA);

  // issue tile B's ea gathers now — latency hides under tile A's store phase
  fvec4 rB[2][2][2];
#pragma unroll
  for(int mt=0;mt<2;mt++){
    const float* p = ea + (size_t)eB[mt]*NG;
#pragma unroll
    for(int kt=0;kt<2;kt++){
      const float* q = p + kt*32 + quad*8;
      rB[mt][kt][0] = __builtin_nontemporal_load((const fvec4*)q);
      rB[mt][kt][1] = __builtin_nontemporal_load((const fvec4*)(q+4));
    }
  }

  store_tile(accA, tile0);

  f32x4 accB[2][8];
  convert_mfma(rB, accB);
  store_tile(accB, tile0+1);
}

// ---------------- cfC = fp16(C @ cfW.T + cfb) on nodes, LDS-transposed stores ----------------
__global__ __launch_bounds__(256,3) void k_cf(
  const float* __restrict__ C, const float* __restrict__ cfW,
  const float* __restrict__ cfb, short* __restrict__ cfC)
{
  __shared__ short ldsW[8*4*64*8];     // 32 KB
  __shared__ short ldsT[4*16*TPAD];    // 17408 B
  stage_w<8,4>(cfW, ldsW);
  __syncthreads();
  const int lane = threadIdx.x & 63, wave = threadIdx.x >> 6;
  const int quad = lane>>4, lc = lane&15;
  short* myT = ldsT + wave*16*TPAD;
  const int tile = blockIdx.x*4 + wave;       // 313*4 = 1252 >= 1250 tiles
  if(tile >= NN/16) return;
  const int base = tile*16;
  h16x8 a[4];
  const float* p = C + (size_t)(base + lc)*NB;
#pragma unroll
  for(int kt=0;kt<4;kt++){
    const float* q = p + kt*32 + quad*8;
    float4 c0 = *(const float4*)q, c1 = *(const float4*)(q+4);
    union{ h16x8 v; unsigned u[4]; } t;
    t.u[0]=pkh(c0.x,c0.y); t.u[1]=pkh(c0.z,c0.w); t.u[2]=pkh(c1.x,c1.y); t.u[3]=pkh(c1.z,c1.w);
    a[kt] = t.v;
  }
  f32x4 acc[8];
  f32x4 z = {0.f,0.f,0.f,0.f};
#pragma unroll
  for(int n2=0;n2<8;n2++) acc[n2] = z;
#pragma unroll
  for(int kt=0;kt<4;kt++)
#pragma unroll
    for(int n2=0;n2<8;n2++){
      h16x8 b = *(const h16x8*)(ldsW + ((size_t)(n2*4+kt)*64 + lane)*8);
      acc[n2] = __builtin_amdgcn_mfma_f32_16x16x32_f16(a[kt], b, acc[n2], 0, 0, 0);
    }
#pragma unroll
  for(int n2=0;n2<8;n2++){
    float bias = cfb[n2*16 + lc];
#pragma unroll
    for(int r=0;r<4;r++)
      myT[(quad*4 + r)*TPAD + n2*16 + lc] = f2h(acc[n2][r] + bias);
  }
  short* gout = cfC + (size_t)base*NB;
#pragma unroll
  for(int i=0;i<4;i++){
    int s_ = i*512 + lane*8;
    int row = s_ >> 7, col = s_ & 127;
    uint4 vv = *(const uint4*)(myT + row*TPAD + col);
    *(uint4*)(gout + s_) = vv;
  }
}

// ---------------- edge kernel: 16-edge tiles, software-pipelined, fp16 ----------------
// C += scatter(tanh((cfC[src] * dft) @ fcW.T)), edges dst-sorted, atomics per segment.
// Footprint history: 32-edge tiles = 112 arch + 64 acc = 176/wave -> 2 waves/SIMD
// (512-reg pool/SIMD), all pipes <30% busy. Register caps spill (r2: cap84; r4:
// cap128 with 64-AGPR acc -> 64 arch, WRITE 257MB). Fix: halve the tile ->
// staging 64 dwords + acc 32 -> ~120-130/wave -> 3-4 waves/SIMD, uncapped.
#define ETPW 4
__global__ __launch_bounds__(256,2) void k_edge(
    const short* __restrict__ cfC, const short* __restrict__ dft,
    const int2* __restrict__ sd,
    const float* __restrict__ fcW, float* __restrict__ C)
{
  __shared__ short ldsW[8*4*64*8];   // 32 KB
  stage_w<8,4>(fcW, ldsW);
  __syncthreads();
  const int lane = threadIdx.x & 63, wave = threadIdx.x >> 6;
  const int quad = lane>>4, lc = lane&15;
  const int tile0 = (blockIdx.x*4 + wave)*ETPW;  // 2500*4*4 = 40000 tiles of 16 edges

  int   sv[2];        // [stage] src node id (row lc)
  int   dv[2];        // [stage] dst node id (row lc)
  uint4 cc[2][4];     // [stage][kt] raw cfC
  uint4 dd[2][4];     // [stage][kt] raw dft

  // ---- prologue: stage 0 = tile0 ----
  {
    const int base = tile0*16;
    int2 s0 = sd[base + lc];
    sv[0] = s0.x; dv[0] = s0.y;
    const short* dp = dft + (size_t)(base + lc)*NB;
#pragma unroll
    for(int kt=0;kt<4;kt++) dd[0][kt] = *(const uint4*)(dp + kt*32 + quad*8);
    const short* cp = cfC + (size_t)sv[0]*NB;
#pragma unroll
    for(int kt=0;kt<4;kt++) cc[0][kt] = *(const uint4*)(cp + kt*32 + quad*8);
  }

#pragma unroll
  for(int t=0; t<ETPW; t++){
    const int cur = t & 1, nxt = cur ^ 1;

    // ---- issue next tile's index load + dft stream (no srcv dependence) ----
    if(t+1 < ETPW){
      const int nbase = (tile0 + t + 1)*16;
      int2 s0 = sd[nbase + lc];
      sv[nxt] = s0.x; dv[nxt] = s0.y;
      const short* dp = dft + (size_t)(nbase + lc)*NB;
#pragma unroll
      for(int kt=0;kt<4;kt++) dd[nxt][kt] = *(const uint4*)(dp + kt*32 + quad*8);
    }

    // ---- convert (packed fp16 mul) + MFMA current tile ----
    f32x4 acc[8];
    f32x4 z = {0.f,0.f,0.f,0.f};
#pragma unroll
    for(int n2=0;n2<8;n2++) acc[n2] = z;
#pragma unroll
    for(int kt=0;kt<4;kt++){
      h16x8 a;
      {
        union{ h16x8 v; unsigned u[4]; } t0;
        uint4 c0 = cc[cur][kt], d0 = dd[cur][kt];
        t0.u[0] = pkmul(c0.x, d0.x); t0.u[1] = pkmul(c0.y, d0.y);
        t0.u[2] = pkmul(c0.z, d0.z); t0.u[3] = pkmul(c0.w, d0.w);
        a = t0.v;
      }
#pragma unroll
      for(int n2=0;n2<8;n2++){
        h16x8 b = *(const h16x8*)(ldsW + ((size_t)(n2*4 + kt)*64 + lane)*8);
        acc[n2] = __builtin_amdgcn_mfma_f32_16x16x32_f16(a, b, acc[n2], 0, 0, 0);
      }
    }

    // ---- issue next tile's cfC gather (srcv arrived while MFMAs ran) ----
    if(t+1 < ETPW){
      const short* cp = cfC + (size_t)sv[nxt]*NB;
#pragma unroll
      for(int kt=0;kt<4;kt++) cc[nxt][kt] = *(const uint4*)(cp + kt*32 + quad*8);
    }

    // ---- tanh ----
#pragma unroll
    for(int n2=0;n2<8;n2++)
#pragma unroll
      for(int r=0;r<4;r++) acc[n2][r] = tanh_fast(acc[n2][r]);

    // ---- segmented reduction over dst (perm-sorted) + quad-distributed atomics ----
    const int di = dv[cur];
    const int dshift = __shfl_up(di, 1);
    const int dprev = (lc > 0) ? dshift : -1;
    unsigned long long mm = __ballot(di != dprev) & 0xFFFFull;
    while(mm){
      int lo = __ffsll(mm) - 1;
      mm &= mm - 1;
      int hi = mm ? (__ffsll(mm) - 1) : 16;
      int v = __shfl(di, lo);
      float sums[8];
#pragma unroll
      for(int n2=0;n2<8;n2++) sums[n2] = 0.f;
#pragma unroll
      for(int r=0; r<4; r++){
        int e2 = quad*4 + r;
        float sel = (e2 >= lo && e2 < hi) ? 1.f : 0.f;
#pragma unroll
        for(int n2=0;n2<8;n2++) sums[n2] = __builtin_fmaf(acc[n2][r], sel, sums[n2]);
      }
#pragma unroll
      for(int n2=0;n2<8;n2++){
        sums[n2] += __shfl_xor(sums[n2], 16);
        sums[n2] += __shfl_xor(sums[n2], 32);
      }
      const int n2w = quad*2;
      atomicAdd(&C[(size_t)v*NB + n2w*16 + lc],     sums[n2w]);
      atomicAdd(&C[(size_t)v*NB + (n2w+1)*16 + lc], sums[n2w+1]);
    }
  }
}

// ---------------- readout: out += pool(tanh(C@r1W.T + r1b)@r2W.T + r2b) ----------------
__global__ __launch_bounds__(256,2) void k_readout(
  const float* __restrict__ C, const float* __restrict__ r1W, const float* __restrict__ r1b,
  const float* __restrict__ r2W, const float* __restrict__ r2b,
  const int* __restrict__ batch, float* __restrict__ out)
{
  __shared__ short ldsW[16*4*64*8];  // 64 KB
  stage_w<16,4>(r1W, ldsW);
  __syncthreads();
  const int lane = threadIdx.x & 63, wave = threadIdx.x >> 6;
  const int quad = lane>>4, lc = lane&15;
  const int base = (blockIdx.x*4 + wave)*16;
  if(base >= NN) return;
  int node = base + lc; if(node > NN-1) node = NN-1;
  h16x8 a[4];
  const float* p = C + (size_t)node*NB;
#pragma unroll
  for(int kt=0;kt<4;kt++){
    const float* q = p + kt*32 + quad*8;
    float4 c0 = *(const float4*)q, c1 = *(const float4*)(q+4);
    union{ h16x8 v; unsigned u[4]; } t;
    t.u[0]=pkh(c0.x,c0.y); t.u[1]=pkh(c0.z,c0.w); t.u[2]=pkh(c1.x,c1.y); t.u[3]=pkh(c1.z,c1.w);
    a[kt] = t.v;
  }
  f32x4 acc[16];
  f32x4 z = {0.f,0.f,0.f,0.f};
#pragma unroll
  for(int nt=0;nt<16;nt++) acc[nt] = z;
#pragma unroll
  for(int kt=0;kt<4;kt++)
#pragma unroll
    for(int nt=0;nt<16;nt++){
      h16x8 b = *(const h16x8*)(ldsW + ((size_t)(nt*4+kt)*64 + lane)*8);
      acc[nt] = __builtin_amdgcn_mfma_f32_16x16x32_f16(a[kt], b, acc[nt], 0, 0, 0);
    }
#pragma unroll
  for(int nt=0;nt<16;nt++){
    float bias = r1b[nt*16 + lc];
#pragma unroll
    for(int r=0;r<4;r++) acc[nt][r] = tanh_fast(acc[nt][r] + bias);
  }
#pragma unroll
  for(int r=0;r<4;r++){
    int nd = base + quad*4 + r;
#pragma unroll
    for(int o=0;o<4;o++){
      float ps = 0.f;
#pragma unroll
      for(int nt=0;nt<16;nt++) ps = __builtin_fmaf(acc[nt][r], r2W[(size_t)o*NH + nt*16 + lc], ps);
      ps += __shfl_xor(ps, 1);
      ps += __shfl_xor(ps, 2);
      ps += __shfl_xor(ps, 4);
      ps += __shfl_xor(ps, 8);
      if(lc == 0 && nd < NN) atomicAdd(&out[batch[nd]*4 + o], ps + r2b[o]);
    }
  }
}

extern "C" void kernel_launch(void* const* d_in, const int* in_sizes, int n_in,
                              void* d_out, int out_size, void* d_ws, size_t ws_size,
                              hipStream_t stream) {
  const int*   Z      = (const int*)d_in[0];
  const int*   ei     = (const int*)d_in[1];
  const float* ea     = (const float*)d_in[2];
  const int*   batch  = (const int*)d_in[3];
  const float* embedW = (const float*)d_in[4];
  const float* cfW    = (const float*)d_in[5];
  const float* cfb    = (const float*)d_in[6];
  const float* dfW    = (const float*)d_in[7];
  const float* dfb    = (const float*)d_in[8];
  const float* fcW    = (const float*)d_in[9];
  const float* r1W    = (const float*)d_in[10];
  const float* r1b    = (const float*)d_in[11];
  const float* r2W    = (const float*)d_in[12];
  const float* r2b    = (const float*)d_in[13];
  const int* src = ei;
  const int* dst = ei + NE;

  char* p = (char*)d_ws;
  auto alloc = [&](size_t b){ char* r = p; p += (b + 255) & ~(size_t)255; return r; };
  float* CA    = (float*)alloc((size_t)NN*NB*4);
  short* cfC   = (short*)alloc((size_t)NN*NB*2);
  short* dft   = (short*)alloc((size_t)NE*NB*2);
  int*   cnt   = (int*)alloc((size_t)NN*4);
  int*   cursor= (int*)alloc((size_t)NN*4);
  int*   perm  = (int*)alloc((size_t)NE*4);
  int2*  sd    = (int2*)alloc((size_t)NE*8);
  size_t needed = (size_t)(p - (char*)d_ws);

  (void)hipMemsetAsync(d_out, 0, (size_t)out_size*sizeof(float), stream);
  if(needed > ws_size) return;   // all-zero output = ws-too-small diagnostic

  (void)hipMemsetAsync(cnt, 0, (size_t)NN*4, stream);
  k_prep0<<<2500, 256, 0, stream>>>(Z, embedW, CA, dst, cnt);
  k_scan <<<1,   1024, 0, stream>>>(cnt, cursor);
  k_fill <<<2500, 256, 0, stream>>>(src, dst, cursor, perm, sd);
  k_dprep<<<2500, 256, 0, stream>>>(ea, perm, dfW, dfb, dft);

  for(int it = 0; it < 3; it++){
    k_cf  <<<313,  256, 0, stream>>>(CA, cfW, cfb, cfC);
    k_edge<<<2500, 256, 0, stream>>>(cfC, dft, sd, fcW, CA);
  }
  k_readout<<<313, 256, 0, stream>>>(CA, r1W, r1b, r2W, r2b, batch, (float*)d_out);
}

// Round 6
// 651.670 us; speedup vs baseline: 1.4954x; 1.0071x over previous
//
#include <hip/hip_runtime.h>
#include <cstdint>

#define NN 20000     // nodes
#define NE 640000    // edges
#define NB 128       // basis
#define NG 64        // gaussians
#define NH 256       // hidden

typedef __attribute__((ext_vector_type(8))) _Float16 h16x8;
typedef __attribute__((ext_vector_type(4))) float f32x4;
typedef __attribute__((ext_vector_type(4))) float fvec4;
typedef __attribute__((ext_vector_type(4))) unsigned uvec4;

__device__ __forceinline__ unsigned fbits(float f){ union{float f; unsigned u;} v; v.f=f; return v.u; }

// pack two f32 -> packed fp16 dword, round-toward-zero (1 instr): low half = a
__device__ __forceinline__ unsigned pkh(float a, float b){
  auto t = __builtin_amdgcn_cvt_pkrtz(a, b);
  return __builtin_bit_cast(unsigned, t);
}
// pack two f32 -> packed fp16 dword, RNE (for weights; one-time cost)
__device__ __forceinline__ unsigned pkh_rne(float a, float b){
  union{ _Float16 h[2]; unsigned u; } v;
  v.h[0] = (_Float16)a; v.h[1] = (_Float16)b; return v.u;
}
// packed fp16 pair * packed fp16 pair -> packed fp16 products (1 instr)
__device__ __forceinline__ unsigned pkmul(unsigned a, unsigned b){
  unsigned r; asm("v_pk_mul_f16 %0, %1, %2" : "=v"(r) : "v"(a), "v"(b)); return r;
}
__device__ __forceinline__ short f2h(float f){
  union{ _Float16 h[2]; short s[2]; } v; v.h[0] = (_Float16)f; return v.s[0];
}

__device__ __forceinline__ float tanh_fast(float x){
  float t = __builtin_amdgcn_exp2f(x * 2.8853900817779268f);
  return __builtin_fmaf(-2.f, __builtin_amdgcn_rcpf(t + 1.f), 1.f);
}

// async global->LDS DMA, 16B per lane, dest = uniform base + lane*16 (HW)
__device__ __forceinline__ void load_lds16(const void* g, void* l){
  __builtin_amdgcn_global_load_lds(
    (const __attribute__((address_space(1))) unsigned*)g,
    (__attribute__((address_space(3))) unsigned*)l, 16, 0, 0);
}

// Stage W[N=NT*16][K=KT*32] (f32) as fp16 MFMA B-fragments into LDS.
template<int NT, int KT>
__device__ __forceinline__ void stage_w(const float* __restrict__ W, short* lds){
  const int total = NT*KT*64;
  for(int c = (int)threadIdx.x; c < total; c += 256){
    int lane = c & 63;
    int kt = (c >> 6) % KT;
    int n  = c / (64*KT);
    int row = n*16 + (lane & 15);
    int col = kt*32 + (lane >> 4)*8;
    const float* p = W + (size_t)row*(KT*32) + col;
    unsigned* d = (unsigned*)(lds + (size_t)c*8);
#pragma unroll
    for(int j=0;j<4;j++) d[j] = pkh_rne(p[2*j], p[2*j+1]);
  }
}

// ---------------- fused embed + dst histogram ----------------
__global__ void k_prep0(const int* __restrict__ Z, const float* __restrict__ E,
                        float* __restrict__ C, const int* __restrict__ dst, int* __restrict__ cnt){
  int i = blockIdx.x*256 + threadIdx.x;    // exactly NN*32 == NE == 640000
  int node = i >> 5, k4 = i & 31;
  ((float4*)C)[i] = ((const float4*)(E + (size_t)Z[node]*NB))[k4];
  atomicAdd(&cnt[dst[i]], 1);
}

__global__ __launch_bounds__(1024) void k_scan(const int* __restrict__ cnt, int* __restrict__ cur){
  __shared__ int lds[1024];
  const int t = threadIdx.x;
  const int base = t*20;
  int4 v[5];
#pragma unroll
  for(int j=0;j<5;j++) v[j] = ((const int4*)(cnt + base))[j];
  const int* ve = (const int*)v;
  int loc[20]; int s = 0;
#pragma unroll
  for(int j=0;j<20;j++){ int c = (base+j < NN) ? ve[j] : 0; loc[j] = s; s += c; }
  lds[t] = s;
  __syncthreads();
  for(int off=1; off<1024; off<<=1){
    int x = (t >= off) ? lds[t-off] : 0;
    __syncthreads();
    lds[t] += x;
    __syncthreads();
  }
  int prefix = (t > 0) ? lds[t-1] : 0;
#pragma unroll
  for(int j=0;j<20;j++){ int i = base+j; if(i<NN) cur[i] = prefix + loc[j]; }
}

__global__ void k_fill(const int* __restrict__ src, const int* __restrict__ dst,
                       int* __restrict__ cur, int* __restrict__ perm,
                       int2* __restrict__ sd){
  int e = blockIdx.x*256 + threadIdx.x;
  if(e < NE){
    int v = dst[e];
    int p = atomicAdd(&cur[v], 1);
    perm[p] = e;
    sd[p] = make_int2(src[e], v);
  }
}

// ---------------- d_feat = edge_attr[perm] @ dfW.T + dfb ----------------
// fp16, perm order. OUTPUT LAYOUT CHANGE: dft is stored in MFMA-fragment order,
// 16-edge tiles of 2048 shorts: short_off(tile16, kt, lane) = tile16*2048 +
// kt*512 + lane*8, holding d_feat[edge = tile16*16 + (lane&15)][col =
// kt*32 + (lane>>4)*8 .. +8]. This makes k_edge's global_load_lds (linear
// dest) directly ds_read-able bank-conflict-free (rule #21: no swizzle needed
// because LDS-linear == read order).
#define TPAD 136
__global__ __launch_bounds__(256,3) void k_dprep(
  const float* __restrict__ ea, const int* __restrict__ perm,
  const float* __restrict__ dfW, const float* __restrict__ dfb, short* __restrict__ dft)
{
  __shared__ short ldsW[8*2*64*8];     // 16 KB
  __shared__ short ldsT[4*32*TPAD];    // 34816 B
  stage_w<8,2>(dfW, ldsW);
  __syncthreads();
  const int lane = threadIdx.x & 63, wave = threadIdx.x >> 6;
  const int quad = lane>>4, lc = lane&15;
  short* myT = ldsT + wave*32*TPAD;
  const int tile0 = (blockIdx.x*4 + wave)*2;   // 2500*4*2 = 20000 32-edge tiles

  float bias[8];
#pragma unroll
  for(int n2=0;n2<8;n2++) bias[n2] = dfb[n2*16 + lc];

  // perm indices for both tiles (independent loads, issued together)
  int eA[2], eB[2];
#pragma unroll
  for(int mt=0;mt<2;mt++){
    eA[mt] = perm[ tile0   *32 + mt*16 + lc];
    eB[mt] = perm[(tile0+1)*32 + mt*16 + lc];
  }

  // raw ea gathers, tile A
  fvec4 rA[2][2][2];
#pragma unroll
  for(int mt=0;mt<2;mt++){
    const float* p = ea + (size_t)eA[mt]*NG;
#pragma unroll
    for(int kt=0;kt<2;kt++){
      const float* q = p + kt*32 + quad*8;
      rA[mt][kt][0] = __builtin_nontemporal_load((const fvec4*)q);
      rA[mt][kt][1] = __builtin_nontemporal_load((const fvec4*)(q+4));
    }
  }

  f32x4 z = {0.f,0.f,0.f,0.f};

  auto convert_mfma = [&](fvec4 (&raw)[2][2][2], f32x4 (&acc)[2][8]){
#pragma unroll
    for(int mt=0;mt<2;mt++)
#pragma unroll
      for(int n2=0;n2<8;n2++) acc[mt][n2] = z;
#pragma unroll
    for(int kt=0;kt<2;kt++){
      h16x8 a0, a1;
      {
        union{ h16x8 v; unsigned u[4]; } t0, t1;
        fvec4 c0 = raw[0][kt][0], c1 = raw[0][kt][1];
        fvec4 d0 = raw[1][kt][0], d1 = raw[1][kt][1];
        t0.u[0]=pkh(c0.x,c0.y); t0.u[1]=pkh(c0.z,c0.w); t0.u[2]=pkh(c1.x,c1.y); t0.u[3]=pkh(c1.z,c1.w);
        t1.u[0]=pkh(d0.x,d0.y); t1.u[1]=pkh(d0.z,d0.w); t1.u[2]=pkh(d1.x,d1.y); t1.u[3]=pkh(d1.z,d1.w);
        a0 = t0.v; a1 = t1.v;
      }
#pragma unroll
      for(int n2=0;n2<8;n2++){
        h16x8 b = *(const h16x8*)(ldsW + ((size_t)(n2*2+kt)*64 + lane)*8);
        acc[0][n2] = __builtin_amdgcn_mfma_f32_16x16x32_f16(a0, b, acc[0][n2], 0, 0, 0);
        acc[1][n2] = __builtin_amdgcn_mfma_f32_16x16x32_f16(a1, b, acc[1][n2], 0, 0, 0);
      }
    }
  };

  auto store_tile = [&](f32x4 (&acc)[2][8], int tile){   // tile = 32-edge index
#pragma unroll
    for(int n2=0;n2<8;n2++)
#pragma unroll
      for(int mt=0;mt<2;mt++)
#pragma unroll
        for(int r=0;r<4;r++)
          myT[(mt*16 + quad*4 + r)*TPAD + n2*16 + lc] = f2h(acc[mt][n2][r] + bias[n2]);
    // emit fragment order: 2 x 16-edge subtiles of 2048 shorts
    short* gout = dft + (size_t)tile*4096;
#pragma unroll
    for(int s16=0;s16<2;s16++)
#pragma unroll
      for(int kt=0;kt<4;kt++){
        uvec4 vv = *(const uvec4*)(myT + (size_t)(s16*16 + lc)*TPAD + kt*32 + quad*8);
        __builtin_nontemporal_store(vv, (uvec4*)(gout + s16*2048 + kt*512 + lane*8));
      }
  };

  // tile A: convert + MFMA
  f32x4 accA[2][8];
  convert_mfma(rA, accA);

  // issue tile B's ea gathers now — latency hides under tile A's store phase
  fvec4 rB[2][2][2];
#pragma unroll
  for(int mt=0;mt<2;mt++){
    const float* p = ea + (size_t)eB[mt]*NG;
#pragma unroll
    for(int kt=0;kt<2;kt++){
      const float* q = p + kt*32 + quad*8;
      rB[mt][kt][0] = __builtin_nontemporal_load((const fvec4*)q);
      rB[mt][kt][1] = __builtin_nontemporal_load((const fvec4*)(q+4));
    }
  }

  store_tile(accA, tile0);

  f32x4 accB[2][8];
  convert_mfma(rB, accB);
  store_tile(accB, tile0+1);
}

// ---------------- cfC = fp16(C @ cfW.T + cfb) on nodes, LDS-transposed stores ----------------
__global__ __launch_bounds__(256,3) void k_cf(
  const float* __restrict__ C, const float* __restrict__ cfW,
  const float* __restrict__ cfb, short* __restrict__ cfC)
{
  __shared__ short ldsW[8*4*64*8];     // 32 KB
  __shared__ short ldsT[4*16*TPAD];    // 17408 B
  stage_w<8,4>(cfW, ldsW);
  __syncthreads();
  const int lane = threadIdx.x & 63, wave = threadIdx.x >> 6;
  const int quad = lane>>4, lc = lane&15;
  short* myT = ldsT + wave*16*TPAD;
  const int tile = blockIdx.x*4 + wave;       // 313*4 = 1252 >= 1250 tiles
  if(tile >= NN/16) return;
  const int base = tile*16;
  h16x8 a[4];
  const float* p = C + (size_t)(base + lc)*NB;
#pragma unroll
  for(int kt=0;kt<4;kt++){
    const float* q = p + kt*32 + quad*8;
    float4 c0 = *(const float4*)q, c1 = *(const float4*)(q+4);
    union{ h16x8 v; unsigned u[4]; } t;
    t.u[0]=pkh(c0.x,c0.y); t.u[1]=pkh(c0.z,c0.w); t.u[2]=pkh(c1.x,c1.y); t.u[3]=pkh(c1.z,c1.w);
    a[kt] = t.v;
  }
  f32x4 acc[8];
  f32x4 z = {0.f,0.f,0.f,0.f};
#pragma unroll
  for(int n2=0;n2<8;n2++) acc[n2] = z;
#pragma unroll
  for(int kt=0;kt<4;kt++)
#pragma unroll
    for(int n2=0;n2<8;n2++){
      h16x8 b = *(const h16x8*)(ldsW + ((size_t)(n2*4+kt)*64 + lane)*8);
      acc[n2] = __builtin_amdgcn_mfma_f32_16x16x32_f16(a[kt], b, acc[n2], 0, 0, 0);
    }
#pragma unroll
  for(int n2=0;n2<8;n2++){
    float bias = cfb[n2*16 + lc];
#pragma unroll
    for(int r=0;r<4;r++)
      myT[(quad*4 + r)*TPAD + n2*16 + lc] = f2h(acc[n2][r] + bias);
  }
  short* gout = cfC + (size_t)base*NB;
#pragma unroll
  for(int i=0;i<4;i++){
    int s_ = i*512 + lane*8;
    int row = s_ >> 7, col = s_ & 127;
    uint4 vv = *(const uint4*)(myT + row*TPAD + col);
    *(uint4*)(gout + s_) = vv;
  }
}

// ---------------- edge kernel: global_load_lds-staged dft, counted vmcnt ----------------
// C += scatter(tanh((cfC[src] * dft) @ fcW.T)), edges dst-sorted, atomics per segment.
// Per-tile pipeline (ETPW=8, fully unrolled, static indices):
//   S1: DMA-stage dft(t+1) -> LDS buf[nxt] (4x global_load_lds, no VGPR cost,
//       cannot be sunk by regalloc) + load sd(t+2)
//   S2: s_waitcnt vmcnt(5) + sched_barrier(0)  -- stage(t), cc(t), sd(t+1) landed
//   S3: issue cc(t+1) per-lane gather (address from sd(t+1), loaded 2 tiles ago)
//   S4: ds_read buf[cur] (fragment order -> uniform bank spread) + pkmul + MFMA
//   S5: tanh + segmented reduce + atomics
// LDS: 32KB weights + 4 waves x 2 x 4KB dft dbuf = 64KB -> 2 blocks/CU.
#define ETPW 8
__global__ __launch_bounds__(256,2) void k_edge(
    const short* __restrict__ cfC, const short* __restrict__ dft,
    const int2* __restrict__ sd,
    const float* __restrict__ fcW, float* __restrict__ C)
{
  __shared__ short ldsW[8*4*64*8];   // 32 KB
  __shared__ short ldsD[4*2*2048];   // 32 KB: 4 waves x 2 bufs x 4KB
  stage_w<8,4>(fcW, ldsW);
  __syncthreads();
  const int lane = threadIdx.x & 63, wave = threadIdx.x >> 6;
  const int quad = lane>>4, lc = lane&15;
  const int tile0 = (blockIdx.x*4 + wave)*ETPW;  // 1250*4*8 = 40000 16-edge tiles
  short* dbuf = ldsD + wave*4096;

  auto stage = [&](int t16, int b){
    const char* g = (const char*)(dft + (size_t)t16*2048);
    short* d = dbuf + b*2048;
#pragma unroll
    for(int j=0;j<4;j++)
      load_lds16(g + j*1024 + (size_t)lane*16, d + j*512);
  };

  // ---- prologue ----
  int2 sA = sd[(size_t)tile0*16 + lc];        // sd(t0)
  int2 sB = sd[(size_t)(tile0+1)*16 + lc];    // sd(t0+1)
  int2 sC = sB;
  stage(tile0, 0);
  uint4 cc[2][4];
  {
    const short* cp = cfC + (size_t)sA.x*NB;
#pragma unroll
    for(int kt=0;kt<4;kt++) cc[0][kt] = *(const uint4*)(cp + kt*32 + quad*8);
  }

#pragma unroll
  for(int t=0; t<ETPW; t++){
    const int cur = t & 1, nxt = cur ^ 1;

    // S1: stage next tile's dft (DMA) + sd two ahead
    if(t+1 < ETPW) stage(tile0 + t + 1, nxt);
    if(t+2 < ETPW) sC = sd[(size_t)(tile0 + t + 2)*16 + lc];

    // S2: counted wait — everything older than this iteration's issues is done
    if(t+1 < ETPW){
      if(t+2 < ETPW){ asm volatile("s_waitcnt vmcnt(5)" ::: "memory"); }
      else          { asm volatile("s_waitcnt vmcnt(4)" ::: "memory"); }
    } else          { asm volatile("s_waitcnt vmcnt(0)" ::: "memory"); }
    __builtin_amdgcn_sched_barrier(0);

    // S3: prefetch next tile's cfC gather (sv from sd(t+1))
    if(t+1 < ETPW){
      const short* cp = cfC + (size_t)sB.x*NB;
#pragma unroll
      for(int kt=0;kt<4;kt++) cc[nxt][kt] = *(const uint4*)(cp + kt*32 + quad*8);
    }

    // S4: pkmul + MFMA from LDS dft (fragment order) and cc regs
    f32x4 acc[8];
    f32x4 z = {0.f,0.f,0.f,0.f};
#pragma unroll
    for(int n2=0;n2<8;n2++) acc[n2] = z;
#pragma unroll
    for(int kt=0;kt<4;kt++){
      h16x8 a;
      {
        union{ h16x8 v; unsigned u[4]; } dv_, t0;
        dv_.v = *(const h16x8*)(dbuf + cur*2048 + kt*512 + lane*8);
        uint4 c0 = cc[cur][kt];
        t0.u[0] = pkmul(c0.x, dv_.u[0]); t0.u[1] = pkmul(c0.y, dv_.u[1]);
        t0.u[2] = pkmul(c0.z, dv_.u[2]); t0.u[3] = pkmul(c0.w, dv_.u[3]);
        a = t0.v;
      }
#pragma unroll
      for(int n2=0;n2<8;n2++){
        h16x8 b = *(const h16x8*)(ldsW + ((size_t)(n2*4 + kt)*64 + lane)*8);
        acc[n2] = __builtin_amdgcn_mfma_f32_16x16x32_f16(a, b, acc[n2], 0, 0, 0);
      }
    }

    // S5: tanh + segmented reduce + atomics
#pragma unroll
    for(int n2=0;n2<8;n2++)
#pragma unroll
      for(int r=0;r<4;r++) acc[n2][r] = tanh_fast(acc[n2][r]);

    const int di = sA.y;
    const int dshift = __shfl_up(di, 1);
    const int dprev = (lc > 0) ? dshift : -1;
    unsigned long long mm = __ballot(di != dprev) & 0xFFFFull;
    while(mm){
      int lo = __ffsll(mm) - 1;
      mm &= mm - 1;
      int hi = mm ? (__ffsll(mm) - 1) : 16;
      int v = __shfl(di, lo);
      float sums[8];
#pragma unroll
      for(int n2=0;n2<8;n2++) sums[n2] = 0.f;
#pragma unroll
      for(int r=0; r<4; r++){
        int e2 = quad*4 + r;
        float sel = (e2 >= lo && e2 < hi) ? 1.f : 0.f;
#pragma unroll
        for(int n2=0;n2<8;n2++) sums[n2] = __builtin_fmaf(acc[n2][r], sel, sums[n2]);
      }
#pragma unroll
      for(int n2=0;n2<8;n2++){
        sums[n2] += __shfl_xor(sums[n2], 16);
        sums[n2] += __shfl_xor(sums[n2], 32);
      }
      const int n2w = quad*2;
      atomicAdd(&C[(size_t)v*NB + n2w*16 + lc],     sums[n2w]);
      atomicAdd(&C[(size_t)v*NB + (n2w+1)*16 + lc], sums[n2w+1]);
    }

    // rotate sd pipeline
    sA = sB; sB = sC;
  }
}

// ---------------- readout: out += pool(tanh(C@r1W.T + r1b)@r2W.T + r2b) ----------------
__global__ __launch_bounds__(256,2) void k_readout(
  const float* __restrict__ C, const float* __restrict__ r1W, const float* __restrict__ r1b,
  const float* __restrict__ r2W, const float* __restrict__ r2b,
  const int* __restrict__ batch, float* __restrict__ out)
{
  __shared__ short ldsW[16*4*64*8];  // 64 KB
  stage_w<16,4>(r1W, ldsW);
  __syncthreads();
  const int lane = threadIdx.x & 63, wave = threadIdx.x >> 6;
  const int quad = lane>>4, lc = lane&15;
  const int base = (blockIdx.x*4 + wave)*16;
  if(base >= NN) return;
  int node = base + lc; if(node > NN-1) node = NN-1;
  h16x8 a[4];
  const float* p = C + (size_t)node*NB;
#pragma unroll
  for(int kt=0;kt<4;kt++){
    const float* q = p + kt*32 + quad*8;
    float4 c0 = *(const float4*)q, c1 = *(const float4*)(q+4);
    union{ h16x8 v; unsigned u[4]; } t;
    t.u[0]=pkh(c0.x,c0.y); t.u[1]=pkh(c0.z,c0.w); t.u[2]=pkh(c1.x,c1.y); t.u[3]=pkh(c1.z,c1.w);
    a[kt] = t.v;
  }
  f32x4 acc[16];
  f32x4 z = {0.f,0.f,0.f,0.f};
#pragma unroll
  for(int nt=0;nt<16;nt++) acc[nt] = z;
#pragma unroll
  for(int kt=0;kt<4;kt++)
#pragma unroll
    for(int nt=0;nt<16;nt++){
      h16x8 b = *(const h16x8*)(ldsW + ((size_t)(nt*4+kt)*64 + lane)*8);
      acc[nt] = __builtin_amdgcn_mfma_f32_16x16x32_f16(a[kt], b, acc[nt], 0, 0, 0);
    }
#pragma unroll
  for(int nt=0;nt<16;nt++){
    float bias = r1b[nt*16 + lc];
#pragma unroll
    for(int r=0;r<4;r++) acc[nt][r] = tanh_fast(acc[nt][r] + bias);
  }
#pragma unroll
  for(int r=0;r<4;r++){
    int nd = base + quad*4 + r;
#pragma unroll
    for(int o=0;o<4;o++){
      float ps = 0.f;
#pragma unroll
      for(int nt=0;nt<16;nt++) ps = __builtin_fmaf(acc[nt][r], r2W[(size_t)o*NH + nt*16 + lc], ps);
      ps += __shfl_xor(ps, 1);
      ps += __shfl_xor(ps, 2);
      ps += __shfl_xor(ps, 4);
      ps += __shfl_xor(ps, 8);
      if(lc == 0 && nd < NN) atomicAdd(&out[batch[nd]*4 + o], ps + r2b[o]);
    }
  }
}

extern "C" void kernel_launch(void* const* d_in, const int* in_sizes, int n_in,
                              void* d_out, int out_size, void* d_ws, size_t ws_size,
                              hipStream_t stream) {
  const int*   Z      = (const int*)d_in[0];
  const int*   ei     = (const int*)d_in[1];
  const float* ea     = (const float*)d_in[2];
  const int*   batch  = (const int*)d_in[3];
  const float* embedW = (const float*)d_in[4];
  const float* cfW    = (const float*)d_in[5];
  const float* cfb    = (const float*)d_in[6];
  const float* dfW    = (const float*)d_in[7];
  const float* dfb    = (const float*)d_in[8];
  const float* fcW    = (const float*)d_in[9];
  const float* r1W    = (const float*)d_in[10];
  const float* r1b    = (const float*)d_in[11];
  const float* r2W    = (const float*)d_in[12];
  const float* r2b    = (const float*)d_in[13];
  const int* src = ei;
  const int* dst = ei + NE;

  char* p = (char*)d_ws;
  auto alloc = [&](size_t b){ char* r = p; p += (b + 255) & ~(size_t)255; return r; };
  float* CA    = (float*)alloc((size_t)NN*NB*4);
  short* cfC   = (short*)alloc((size_t)NN*NB*2);
  short* dft   = (short*)alloc((size_t)NE*NB*2);
  int*   cnt   = (int*)alloc((size_t)NN*4);
  int*   cursor= (int*)alloc((size_t)NN*4);
  int*   perm  = (int*)alloc((size_t)NE*4);
  int2*  sd    = (int2*)alloc((size_t)NE*8);
  size_t needed = (size_t)(p - (char*)d_ws);

  (void)hipMemsetAsync(d_out, 0, (size_t)out_size*sizeof(float), stream);
  if(needed > ws_size) return;   // all-zero output = ws-too-small diagnostic

  (void)hipMemsetAsync(cnt, 0, (size_t)NN*4, stream);
  k_prep0<<<2500, 256, 0, stream>>>(Z, embedW, CA, dst, cnt);
  k_scan <<<1,   1024, 0, stream>>>(cnt, cursor);
  k_fill <<<2500, 256, 0, stream>>>(src, dst, cursor, perm, sd);
  k_dprep<<<2500, 256, 0, stream>>>(ea, perm, dfW, dfb, dft);

  for(int it = 0; it < 3; it++){
    k_cf  <<<313,  256, 0, stream>>>(CA, cfW, cfb, cfC);
    k_edge<<<1250, 256, 0, stream>>>(cfC, dft, sd, fcW, CA);
  }
  k_readout<<<313, 256, 0, stream>>>(CA, r1W, r1b, r2W, r2b, batch, (float*)d_out);
}